// Round 19
// baseline (129.754 us; speedup 1.0000x reference)
//
#include <hip/hip_runtime.h>
#include <hip/hip_bf16.h>
#include <cstdint>
#include <cstddef>

#define NA   2048
#define NB   2048
#define DD   512

typedef __attribute__((ext_vector_type(8))) short bf16x8;
typedef __attribute__((ext_vector_type(4))) float f32x4;
typedef unsigned short u16;
typedef unsigned int   u32;

__device__ __forceinline__ u16 f2b_hw(float f) {
    u32 w;
    asm("v_cvt_pk_bf16_f32 %0, %1, %2" : "=v"(w) : "v"(f), "v"(f));
    return (u16)w;
}
__device__ __forceinline__ float b2f(u16 h) {
    return __uint_as_float(((u32)h) << 16);
}
__device__ __forceinline__ u32 umin32(u32 a, u32 b) { return a < b ? a : b; }
__device__ __forceinline__ u32 umax32(u32 a, u32 b) { return a > b ? a : b; }
__device__ __forceinline__ u32 med3u(u32 a, u32 b, u32 c) {
    return umax32(umin32(a, b), umin32(umax32(a, b), c));   // -> v_med3_u32
}
__device__ __forceinline__ bf16x8 cvt8(f32x4 v0, f32x4 v1) {
    u32 w0, w1, w2, w3;
    asm("v_cvt_pk_bf16_f32 %0, %1, %2" : "=v"(w0) : "v"(v0[0]), "v"(v0[1]));
    asm("v_cvt_pk_bf16_f32 %0, %1, %2" : "=v"(w1) : "v"(v0[2]), "v"(v0[3]));
    asm("v_cvt_pk_bf16_f32 %0, %1, %2" : "=v"(w2) : "v"(v1[0]), "v"(v1[1]));
    asm("v_cvt_pk_bf16_f32 %0, %1, %2" : "=v"(w3) : "v"(v1[2]), "v"(v1[3]));
    union { u32 u[4]; bf16x8 v; } cv;
    cv.u[0] = w0; cv.u[1] = w1; cv.u[2] = w2; cv.u[3] = w3;
    return cv.v;
}

#define GLDS16(gsrc, ldst)                                                  \
    __builtin_amdgcn_global_load_lds(                                       \
        (const __attribute__((address_space(1))) void*)(gsrc),              \
        (__attribute__((address_space(3))) void*)(ldst), 16, 0, 0)

// ---------------------------------------------------------------------------
// Fused topk + copy + prep_w. 1D grid of 320 blocks x 512 threads:
//   bid < 256 : exact integer top-4 NN for 128 queries (lax.top_k tie-break)
//               with the fa -> out[:,0:512] copy SOFTWARE-PIPELINED under the
//               VALU distance loop (4 chunks: 8 loads / 128 iters / 8 stores)
//   bid >= 256: prep_w tile — W2T[n][k]=W[512+k][n], WdT=W[k][n]-W[512+k][n]
// ---------------------------------------------------------------------------
__global__ __launch_bounds__(512) void topk_prep(
    const int* __restrict__ ca, const int* __restrict__ cb,
    int* __restrict__ idx_out, float* __restrict__ w_out,
    const float* __restrict__ fa, float* __restrict__ out,
    const float* __restrict__ W, u16* __restrict__ W2T,
    u16* __restrict__ WdT) {

    __shared__ __align__(16) char smem[33280];
    const int bid = blockIdx.x;
    const int tid = threadIdx.x;

    if (bid >= 256) {
        // ================= prep_w tile (64 x 64), 512 threads ==============
        float (*s2)[65] = (float(*)[65])smem;            // 16640 B
        float (*sd)[65] = (float(*)[65])(smem + 16640);  // 16640 B
        const int pid = bid - 256;
        const int kb = (pid >> 3) * 64, nb = (pid & 7) * 64;
        const int c = tid & 63, r0 = tid >> 6;           // r0: 0..7
        #pragma unroll
        for (int p = 0; p < 8; ++p) {
            int r = p * 8 + r0;
            float w1 = W[(size_t)(kb + r) * DD + nb + c];
            float w2 = W[(size_t)(512 + kb + r) * DD + nb + c];
            s2[r][c] = w2;
            sd[r][c] = w1 - w2;
        }
        __syncthreads();
        #pragma unroll
        for (int p = 0; p < 8; ++p) {
            int n = p * 8 + r0;
            W2T[(size_t)(nb + n) * DD + kb + c] = f2b_hw(s2[c][n]);
            WdT[(size_t)(nb + n) * DD + kb + c] = f2b_hw(sd[c][n]);
        }
        return;
    }

    // ================= topk (pipelined with fa -> out copy) ================
    u32* pcb  = (u32*)smem;              // 2048 packed coords, 8 KB
    u32* part = (u32*)(smem + 8192);     // groups 1..3 partials, 6 KB
    const int b  = bid >> 4;
    const int i0 = (bid & 15) << 7;
    for (int p = tid; p < NB; p += 512) {
        const int* c = cb + ((size_t)b * NB + p) * 3;
        pcb[p] = (u32)c[0] | ((u32)c[1] << 8) | ((u32)c[2] << 16);
    }
    __syncthreads();

    int q = tid & 127, g = tid >> 7;
    int i = i0 + q;
    const int* ac = ca + ((size_t)b * NA + i) * 3;
    int ax = ac[0], ay = ac[1], az = ac[2];

    const float* src = fa + (size_t)bid * 128 * DD;
    float*       dst = out + (size_t)bid * 128 * 1024;

    u32 k0 = ~0u, k1 = ~0u, k2 = ~0u, k3 = ~0u;
    int j0 = g * 512;

    #pragma unroll 1
    for (int c = 0; c < 4; ++c) {
        // issue this chunk's copy loads (latency hides under distance VALU)
        f32x4 tr[8];
        #pragma unroll
        for (int k = 0; k < 8; ++k) {
            int f = c * 4096 + k * 512 + tid;
            tr[k] = *(const f32x4*)(src + (size_t)(f >> 7) * DD + (f & 127) * 4);
        }
        // 128 distance iterations
        int jbase = j0 + c * 128;
        #pragma unroll 8
        for (int jj = 0; jj < 128; ++jj) {
            int j = jbase + jj;
            u32 p = pcb[j];
            int dx = ax - (int)(p & 255u);
            int dy = ay - (int)((p >> 8) & 255u);
            int dz = az - (int)(p >> 16);
            u32 s = (u32)(__mul24(dx, dx) + __mul24(dy, dy) + __mul24(dz, dz));
            u32 key = (s << 11) | (u32)j;
            u32 nk0 = umin32(k0, key);
            u32 nk1 = med3u(key, k0, k1);
            u32 nk2 = med3u(key, k1, k2);
            u32 nk3 = med3u(key, k2, k3);
            k0 = nk0; k1 = nk1; k2 = nk2; k3 = nk3;
        }
        // drain this chunk's copy stores
        #pragma unroll
        for (int k = 0; k < 8; ++k) {
            int f = c * 4096 + k * 512 + tid;
            *(f32x4*)(dst + (size_t)(f >> 7) * 1024 + (f & 127) * 4) = tr[k];
        }
    }

    if (g) {
        u32* pp = &part[((g - 1) * 128 + q) * 4];
        pp[0] = k0; pp[1] = k1; pp[2] = k2; pp[3] = k3;
    }
    __syncthreads();
    if (g == 0) {
        #pragma unroll
        for (int L = 0; L < 3; ++L) {
            const u32* pp = &part[(L * 128 + q) * 4];
            #pragma unroll
            for (int t = 0; t < 4; ++t) {
                u32 key = pp[t];
                u32 nk0 = umin32(k0, key);
                u32 nk1 = med3u(key, k0, k1);
                u32 nk2 = med3u(key, k1, k2);
                u32 nk3 = med3u(key, k2, k3);
                k0 = nk0; k1 = nk1; k2 = nk2; k3 = nk3;
            }
        }
        size_t o = ((size_t)b * NA + i) * 4;
        u32 ks[4] = {k0, k1, k2, k3};
        #pragma unroll
        for (int t = 0; t < 4; ++t) {
            idx_out[o + t] = (int)(ks[t] & 2047u);
            float d = sqrtf((float)(ks[t] >> 11)) * (1.0f / 128.0f);
            w_out[o + t] = 0.5f - fminf(d, 0.5f);
        }
    }
}

// ---------------------------------------------------------------------------
// C = A(f32) @ BT^T(bf16). BM=128, BN=256, BK=32, 4 waves (64m x 128n).
// A staged f32 via GLDS16 (src XOR-swizzled), cvt_pk->bf16 at fragment read.
// T4 counted-vmcnt pipeline: STAGE(t+1); vmcnt(8); barrier; compute; barrier.
// FUSED (P path): fused bias+relu+Q[idx]-gather epilogue with DEPTH-3 gather
// pipeline (idx hoisted before K-loop, wb hoisted before Ps write).
// ---------------------------------------------------------------------------
template<bool FUSED>
__global__ __launch_bounds__(256, 1) void gemm_kernel(
    const float* __restrict__ A, const u16* __restrict__ BT,
    u16* __restrict__ C, const int* __restrict__ idxb,
    const float* __restrict__ wb, const float* __restrict__ bias,
    const u16* __restrict__ Qb, float* __restrict__ out) {

    __shared__ __align__(16) char smem[FUSED ? 66560 : 65536];

    const int tid  = threadIdx.x;
    const int lane = tid & 63;
    const int wave = tid >> 6;
    const int m0   = blockIdx.x << 7;
    const int n0   = blockIdx.y << 8;
    const int l15  = lane & 15;
    const int fq   = lane >> 4;              // 0..3
    const int wr   = (wave >> 1) << 6;
    const int wc   = (wave & 1) << 7;

    // ---- staging descriptors: LDS dest linear, SOURCE pre-swizzled --------
    int aflat[4]; const float* asp[4];
    #pragma unroll
    for (int i = 0; i < 4; ++i) {
        int flat = i * 256 + tid;            // A: 128 rows x 8 f32 16B-quads
        int row = flat >> 3, pq = flat & 7;
        aflat[i] = flat;
        asp[i] = A + (size_t)(m0 + row) * DD + ((pq ^ (row & 7)) << 2);
    }
    int bflat[4]; const u16* bsp[4];
    #pragma unroll
    for (int i = 0; i < 4; ++i) {
        int flat = i * 256 + tid;            // B: 256 rows x 4 bf16 16B-quads
        int row = flat >> 2, pq = flat & 3;
        bflat[i] = flat;
        bsp[i] = BT + (size_t)(n0 + row) * DD + ((pq ^ ((row >> 1) & 3)) << 3);
    }

    // ---- fragment LDS byte offsets (same involution on read) --------------
    int aoff[4][2], boff[8];
    #pragma unroll
    for (int mf = 0; mf < 4; ++mf) {
        int R = wr + mf * 16 + l15;
        aoff[mf][0] = R * 128 + (((2 * fq) ^ (R & 7)) << 4);
        aoff[mf][1] = R * 128 + (((2 * fq + 1) ^ (R & 7)) << 4);
    }
    #pragma unroll
    for (int nf = 0; nf < 8; ++nf) {
        int R = wc + nf * 16 + l15;
        boff[nf] = 16384 + R * 64 + ((fq ^ ((R >> 1) & 3)) << 4);
    }

    // FUSED: hoist idx loads (ready at block start; frees tail latency)
    const int g16 = tid >> 4, l16 = tid & 15;
    const int r0g = g16 * 8;
    int4 iv[8];
    if (FUSED) {
        #pragma unroll
        for (int k = 0; k < 8; ++k)
            iv[k] = *(const int4*)(idxb + (size_t)(m0 + r0g + k) * 4);
    }

    f32x4 acc[4][8];
    #pragma unroll
    for (int mf = 0; mf < 4; ++mf)
        #pragma unroll
        for (int nf = 0; nf < 8; ++nf)
            acc[mf][nf] = (f32x4){0.f, 0.f, 0.f, 0.f};

#define STAGE(kk, bufb)                                                      \
    { _Pragma("unroll") for (int i = 0; i < 4; ++i)                          \
          GLDS16(asp[i] + (kk), smem + (bufb) + aflat[i] * 16);              \
      _Pragma("unroll") for (int i = 0; i < 4; ++i)                          \
          GLDS16(bsp[i] + (kk), smem + (bufb) + 16384 + bflat[i] * 16); }

    STAGE(0, 0);

    #pragma unroll 1
    for (int t = 0; t < 16; ++t) {
        const int cur = (t & 1) * 32768;
        if (t < 15) {
            STAGE((t + 1) * 32, 32768 - cur);
            asm volatile("s_waitcnt vmcnt(8)" ::: "memory");   // stage t done
        } else {
            asm volatile("s_waitcnt vmcnt(0)" ::: "memory");
        }
        __builtin_amdgcn_s_barrier();        // all waves' stage t visible

        bf16x8 af[4], bfr[8];
        #pragma unroll
        for (int mf = 0; mf < 4; ++mf) {
            f32x4 lo = *(const f32x4*)(smem + cur + aoff[mf][0]);
            f32x4 hi = *(const f32x4*)(smem + cur + aoff[mf][1]);
            af[mf] = cvt8(lo, hi);
        }
        #pragma unroll
        for (int nf = 0; nf < 8; ++nf)
            bfr[nf] = *(const bf16x8*)(smem + cur + boff[nf]);
        #pragma unroll
        for (int mf = 0; mf < 4; ++mf)
            #pragma unroll
            for (int nf = 0; nf < 8; ++nf)
                acc[mf][nf] = __builtin_amdgcn_mfma_f32_16x16x32_bf16(
                    af[mf], bfr[nf], acc[mf][nf], 0, 0, 0);

        __builtin_amdgcn_s_barrier();        // buf may be overwritten next t
    }

    const int r4 = (lane >> 4) * 4;

    if (!FUSED) {
        #pragma unroll
        for (int mf = 0; mf < 4; ++mf)
            #pragma unroll
            for (int nf = 0; nf < 8; ++nf)
                #pragma unroll
                for (int j = 0; j < 4; ++j) {
                    int row = m0 + wr + mf * 16 + r4 + j;
                    int col = n0 + wc + nf * 16 + l15;
                    C[(size_t)row * DD + col] = f2b_hw(acc[mf][nf][j]);
                }
        return;
    }

    // ---- fused epilogue: P' = acc + bias -> Ps (bf16), gather Q[idx] ------
    const u16* qs = Qb + ((size_t)(m0 >> 11) << 20);   // batch * 2048 * 512

    // hoist wb loads (latency hides under the Ps write below)
    f32x4 wv8[8];
    #pragma unroll
    for (int k = 0; k < 8; ++k)
        wv8[k] = *(const f32x4*)(wb + (size_t)(m0 + r0g + k) * 4);

    float bi[8];
    #pragma unroll
    for (int nf = 0; nf < 8; ++nf)
        bi[nf] = bias[n0 + wc + nf * 16 + l15];

    u16* Ps = (u16*)smem;                    // [128][260] bf16, 66560 B
    #pragma unroll
    for (int mf = 0; mf < 4; ++mf)
        #pragma unroll
        for (int nf = 0; nf < 8; ++nf)
            #pragma unroll
            for (int j = 0; j < 4; ++j)
                Ps[(wr + mf * 16 + r4 + j) * 260 + wc + nf * 16 + l15] =
                    f2b_hw(acc[mf][nf][j] + bi[nf]);

    // depth-3 gather pipeline: three static register banks (rule #20)
    bf16x8 qA0[8], qA1[8], qA2[8];

#define QLOAD(BANK, k)                                                       \
    { const size_t rx = (size_t)iv[k].x * DD, ry = (size_t)iv[k].y * DD,     \
                   rz = (size_t)iv[k].z * DD, rw = (size_t)iv[k].w * DD;     \
      _Pragma("unroll") for (int cc = 0; cc < 2; ++cc) {                     \
          const int col = n0 + cc * 128 + l16 * 8;                           \
          BANK[cc*4+0] = *(const bf16x8*)(qs + rx + col);                    \
          BANK[cc*4+1] = *(const bf16x8*)(qs + ry + col);                    \
          BANK[cc*4+2] = *(const bf16x8*)(qs + rz + col);                    \
          BANK[cc*4+3] = *(const bf16x8*)(qs + rw + col);                    \
      } }

#define QCONSUME(BANK, k)                                                    \
    { f32x4 wv = wv8[k];                                                     \
      _Pragma("unroll") for (int cc = 0; cc < 2; ++cc) {                     \
          const int col = cc * 128 + l16 * 8;                                \
          bf16x8 p8 = *(const bf16x8*)(Ps + (r0g + (k)) * 260 + col);        \
          float o[8];                                                        \
          _Pragma("unroll") for (int j = 0; j < 8; ++j) {                    \
              float p = b2f((u16)p8[j]);                                     \
              float s;                                                       \
              s  = fmaxf(p + b2f((u16)BANK[cc*4+0][j]), 0.f) * wv[0];        \
              s += fmaxf(p + b2f((u16)BANK[cc*4+1][j]), 0.f) * wv[1];        \
              s += fmaxf(p + b2f((u16)BANK[cc*4+2][j]), 0.f) * wv[2];        \
              s += fmaxf(p + b2f((u16)BANK[cc*4+3][j]), 0.f) * wv[3];        \
              o[j] = s;                                                      \
          }                                                                  \
          float* op = out + (size_t)(m0 + r0g + (k)) * 1024 + 512 + n0 + col;\
          *(f32x4*)op       = (f32x4){o[0], o[1], o[2], o[3]};               \
          *(f32x4*)(op + 4) = (f32x4){o[4], o[5], o[6], o[7]};               \
      } }

    // issue three gather batches before the barrier (in flight across it)
    QLOAD(qA0, 0);
    QLOAD(qA1, 1);
    QLOAD(qA2, 2);
    __syncthreads();

    QCONSUME(qA0, 0); QLOAD(qA0, 3);
    QCONSUME(qA1, 1); QLOAD(qA1, 4);
    QCONSUME(qA2, 2); QLOAD(qA2, 5);
    QCONSUME(qA0, 3); QLOAD(qA0, 6);
    QCONSUME(qA1, 4); QLOAD(qA1, 7);
    QCONSUME(qA2, 5);
    QCONSUME(qA0, 6);
    QCONSUME(qA1, 7);
}

extern "C" void kernel_launch(void* const* d_in, const int* in_sizes, int n_in,
                              void* d_out, int out_size, void* d_ws, size_t ws_size,
                              hipStream_t stream) {
    const float* fa   = (const float*)d_in[0];
    const float* fb   = (const float*)d_in[1];
    const float* W    = (const float*)d_in[2];
    const float* bias = (const float*)d_in[3];
    const int*   ca   = (const int*)d_in[4];
    const int*   cb   = (const int*)d_in[5];
    float* out = (float*)d_out;

    char* ws = (char*)d_ws;
    u16*   Qb   = (u16*)(ws);                       // 32 MB bf16 Q
    u16*   W2T  = (u16*)(ws + 33554432);            // 512 KB
    u16*   WdT  = (u16*)(ws + 34078720);            // 512 KB
    int*   idxb = (int*)(ws + 34603008);            // 512 KB
    float* wb   = (float*)(ws + 35127296);          // 512 KB

    topk_prep<<<320, 512, 0, stream>>>(ca, cb, idxb, wb, fa, out,
                                       W, W2T, WdT);

    dim3 gg(256, 2);
    gemm_kernel<false><<<gg, 256, 0, stream>>>(fb, WdT, Qb, nullptr, nullptr,
                                               nullptr, nullptr, nullptr);
    gemm_kernel<true><<<gg, 256, 0, stream>>>(fa, W2T, nullptr, idxb, wb,
                                              bias, Qb, out);
}

// Round 20
// 124.198 us; speedup vs baseline: 1.0447x; 1.0447x over previous
//
#include <hip/hip_runtime.h>
#include <hip/hip_bf16.h>
#include <cstdint>
#include <cstddef>

#define NA   2048
#define NB   2048
#define DD   512

typedef __attribute__((ext_vector_type(8))) short bf16x8;
typedef __attribute__((ext_vector_type(4))) float f32x4;
typedef unsigned short u16;
typedef unsigned int   u32;

__device__ __forceinline__ u16 f2b_hw(float f) {
    u32 w;
    asm("v_cvt_pk_bf16_f32 %0, %1, %2" : "=v"(w) : "v"(f), "v"(f));
    return (u16)w;
}
__device__ __forceinline__ float b2f(u16 h) {
    return __uint_as_float(((u32)h) << 16);
}
__device__ __forceinline__ u32 umin32(u32 a, u32 b) { return a < b ? a : b; }
__device__ __forceinline__ u32 umax32(u32 a, u32 b) { return a > b ? a : b; }
__device__ __forceinline__ u32 med3u(u32 a, u32 b, u32 c) {
    return umax32(umin32(a, b), umin32(umax32(a, b), c));   // -> v_med3_u32
}
__device__ __forceinline__ bf16x8 cvt8(f32x4 v0, f32x4 v1) {
    u32 w0, w1, w2, w3;
    asm("v_cvt_pk_bf16_f32 %0, %1, %2" : "=v"(w0) : "v"(v0[0]), "v"(v0[1]));
    asm("v_cvt_pk_bf16_f32 %0, %1, %2" : "=v"(w1) : "v"(v0[2]), "v"(v0[3]));
    asm("v_cvt_pk_bf16_f32 %0, %1, %2" : "=v"(w2) : "v"(v1[0]), "v"(v1[1]));
    asm("v_cvt_pk_bf16_f32 %0, %1, %2" : "=v"(w3) : "v"(v1[2]), "v"(v1[3]));
    union { u32 u[4]; bf16x8 v; } cv;
    cv.u[0] = w0; cv.u[1] = w1; cv.u[2] = w2; cv.u[3] = w3;
    return cv.v;
}

#define GLDS16(gsrc, ldst)                                                  \
    __builtin_amdgcn_global_load_lds(                                       \
        (const __attribute__((address_space(1))) void*)(gsrc),              \
        (__attribute__((address_space(3))) void*)(ldst), 16, 0, 0)

// ---------------------------------------------------------------------------
// Fused topk + copy + prep_w. 1D grid of 320 blocks x 512 threads:
//   bid < 256 : exact integer top-4 NN for 128 queries (lax.top_k tie-break)
//               with the fa -> out[:,0:512] copy SOFTWARE-PIPELINED under the
//               VALU distance loop (4 chunks: 8 loads / 128 iters / 8 stores)
//   bid >= 256: prep_w tile — W2T[n][k]=W[512+k][n], WdT=W[k][n]-W[512+k][n]
// ---------------------------------------------------------------------------
__global__ __launch_bounds__(512) void topk_prep(
    const int* __restrict__ ca, const int* __restrict__ cb,
    int* __restrict__ idx_out, float* __restrict__ w_out,
    const float* __restrict__ fa, float* __restrict__ out,
    const float* __restrict__ W, u16* __restrict__ W2T,
    u16* __restrict__ WdT) {

    __shared__ __align__(16) char smem[33280];
    const int bid = blockIdx.x;
    const int tid = threadIdx.x;

    if (bid >= 256) {
        // ================= prep_w tile (64 x 64), 512 threads ==============
        float (*s2)[65] = (float(*)[65])smem;            // 16640 B
        float (*sd)[65] = (float(*)[65])(smem + 16640);  // 16640 B
        const int pid = bid - 256;
        const int kb = (pid >> 3) * 64, nb = (pid & 7) * 64;
        const int c = tid & 63, r0 = tid >> 6;           // r0: 0..7
        #pragma unroll
        for (int p = 0; p < 8; ++p) {
            int r = p * 8 + r0;
            float w1 = W[(size_t)(kb + r) * DD + nb + c];
            float w2 = W[(size_t)(512 + kb + r) * DD + nb + c];
            s2[r][c] = w2;
            sd[r][c] = w1 - w2;
        }
        __syncthreads();
        #pragma unroll
        for (int p = 0; p < 8; ++p) {
            int n = p * 8 + r0;
            W2T[(size_t)(nb + n) * DD + kb + c] = f2b_hw(s2[c][n]);
            WdT[(size_t)(nb + n) * DD + kb + c] = f2b_hw(sd[c][n]);
        }
        return;
    }

    // ================= topk (pipelined with fa -> out copy) ================
    u32* pcb  = (u32*)smem;              // 2048 packed coords, 8 KB
    u32* part = (u32*)(smem + 8192);     // groups 1..3 partials, 6 KB
    const int b  = bid >> 4;
    const int i0 = (bid & 15) << 7;
    for (int p = tid; p < NB; p += 512) {
        const int* c = cb + ((size_t)b * NB + p) * 3;
        pcb[p] = (u32)c[0] | ((u32)c[1] << 8) | ((u32)c[2] << 16);
    }
    __syncthreads();

    int q = tid & 127, g = tid >> 7;
    int i = i0 + q;
    const int* ac = ca + ((size_t)b * NA + i) * 3;
    int ax = ac[0], ay = ac[1], az = ac[2];

    const float* src = fa + (size_t)bid * 128 * DD;
    float*       dst = out + (size_t)bid * 128 * 1024;

    u32 k0 = ~0u, k1 = ~0u, k2 = ~0u, k3 = ~0u;
    int j0 = g * 512;

    #pragma unroll 1
    for (int c = 0; c < 4; ++c) {
        // issue this chunk's copy loads (latency hides under distance VALU)
        f32x4 tr[8];
        #pragma unroll
        for (int k = 0; k < 8; ++k) {
            int f = c * 4096 + k * 512 + tid;
            tr[k] = *(const f32x4*)(src + (size_t)(f >> 7) * DD + (f & 127) * 4);
        }
        // 128 distance iterations
        int jbase = j0 + c * 128;
        #pragma unroll 8
        for (int jj = 0; jj < 128; ++jj) {
            int j = jbase + jj;
            u32 p = pcb[j];
            int dx = ax - (int)(p & 255u);
            int dy = ay - (int)((p >> 8) & 255u);
            int dz = az - (int)(p >> 16);
            u32 s = (u32)(__mul24(dx, dx) + __mul24(dy, dy) + __mul24(dz, dz));
            u32 key = (s << 11) | (u32)j;
            u32 nk0 = umin32(k0, key);
            u32 nk1 = med3u(key, k0, k1);
            u32 nk2 = med3u(key, k1, k2);
            u32 nk3 = med3u(key, k2, k3);
            k0 = nk0; k1 = nk1; k2 = nk2; k3 = nk3;
        }
        // drain this chunk's copy stores
        #pragma unroll
        for (int k = 0; k < 8; ++k) {
            int f = c * 4096 + k * 512 + tid;
            *(f32x4*)(dst + (size_t)(f >> 7) * 1024 + (f & 127) * 4) = tr[k];
        }
    }

    if (g) {
        u32* pp = &part[((g - 1) * 128 + q) * 4];
        pp[0] = k0; pp[1] = k1; pp[2] = k2; pp[3] = k3;
    }
    __syncthreads();
    if (g == 0) {
        #pragma unroll
        for (int L = 0; L < 3; ++L) {
            const u32* pp = &part[(L * 128 + q) * 4];
            #pragma unroll
            for (int t = 0; t < 4; ++t) {
                u32 key = pp[t];
                u32 nk0 = umin32(k0, key);
                u32 nk1 = med3u(key, k0, k1);
                u32 nk2 = med3u(key, k1, k2);
                u32 nk3 = med3u(key, k2, k3);
                k0 = nk0; k1 = nk1; k2 = nk2; k3 = nk3;
            }
        }
        size_t o = ((size_t)b * NA + i) * 4;
        u32 ks[4] = {k0, k1, k2, k3};
        #pragma unroll
        for (int t = 0; t < 4; ++t) {
            idx_out[o + t] = (int)(ks[t] & 2047u);
            float d = sqrtf((float)(ks[t] >> 11)) * (1.0f / 128.0f);
            w_out[o + t] = 0.5f - fminf(d, 0.5f);
        }
    }
}

// ---------------------------------------------------------------------------
// C = A(f32) @ BT^T(bf16). BM=128, BN=256, BK=32, 4 waves (64m x 128n).
// A staged f32 via GLDS16 (src XOR-swizzled), cvt_pk->bf16 at fragment read.
// T4 counted-vmcnt pipeline: STAGE(t+1); vmcnt(8); barrier; compute; barrier.
// FUSED (P path): XCD m-swizzle, fused bias+relu+Q[idx]-gather epilogue with
// depth-2 gather pipeline (idx loads hoisted before the K-loop).
// ---------------------------------------------------------------------------
template<bool FUSED>
__global__ __launch_bounds__(256, 1) void gemm_kernel(
    const float* __restrict__ A, const u16* __restrict__ BT,
    u16* __restrict__ C, const int* __restrict__ idxb,
    const float* __restrict__ wb, const float* __restrict__ bias,
    const u16* __restrict__ Qb, float* __restrict__ out) {

    __shared__ __align__(16) char smem[FUSED ? 66560 : 65536];

    const int tid  = threadIdx.x;
    const int lane = tid & 63;
    const int wave = tid >> 6;
    const int mb   = blockIdx.x;
    const int m0   = FUSED ? ((((mb & 7) << 5) | (mb >> 3)) << 7) : (mb << 7);
    const int n0   = blockIdx.y << 8;
    const int l15  = lane & 15;
    const int fq   = lane >> 4;              // 0..3
    const int wr   = (wave >> 1) << 6;
    const int wc   = (wave & 1) << 7;

    // ---- staging descriptors: LDS dest linear, SOURCE pre-swizzled --------
    int aflat[4]; const float* asp[4];
    #pragma unroll
    for (int i = 0; i < 4; ++i) {
        int flat = i * 256 + tid;            // A: 128 rows x 8 f32 16B-quads
        int row = flat >> 3, pq = flat & 7;
        aflat[i] = flat;
        asp[i] = A + (size_t)(m0 + row) * DD + ((pq ^ (row & 7)) << 2);
    }
    int bflat[4]; const u16* bsp[4];
    #pragma unroll
    for (int i = 0; i < 4; ++i) {
        int flat = i * 256 + tid;            // B: 256 rows x 4 bf16 16B-quads
        int row = flat >> 2, pq = flat & 3;
        bflat[i] = flat;
        bsp[i] = BT + (size_t)(n0 + row) * DD + ((pq ^ ((row >> 1) & 3)) << 3);
    }

    // ---- fragment LDS byte offsets (same involution on read) --------------
    int aoff[4][2], boff[8];
    #pragma unroll
    for (int mf = 0; mf < 4; ++mf) {
        int R = wr + mf * 16 + l15;
        aoff[mf][0] = R * 128 + (((2 * fq) ^ (R & 7)) << 4);
        aoff[mf][1] = R * 128 + (((2 * fq + 1) ^ (R & 7)) << 4);
    }
    #pragma unroll
    for (int nf = 0; nf < 8; ++nf) {
        int R = wc + nf * 16 + l15;
        boff[nf] = 16384 + R * 64 + ((fq ^ ((R >> 1) & 3)) << 4);
    }

    // FUSED: hoist idx loads (ready at block start; frees tail latency)
    const int g16 = tid >> 4, l16 = tid & 15;
    const int r0g = g16 * 8;
    int4 iv[8];
    if (FUSED) {
        #pragma unroll
        for (int k = 0; k < 8; ++k)
            iv[k] = *(const int4*)(idxb + (size_t)(m0 + r0g + k) * 4);
    }

    f32x4 acc[4][8];
    #pragma unroll
    for (int mf = 0; mf < 4; ++mf)
        #pragma unroll
        for (int nf = 0; nf < 8; ++nf)
            acc[mf][nf] = (f32x4){0.f, 0.f, 0.f, 0.f};

#define STAGE(kk, bufb)                                                      \
    { _Pragma("unroll") for (int i = 0; i < 4; ++i)                          \
          GLDS16(asp[i] + (kk), smem + (bufb) + aflat[i] * 16);              \
      _Pragma("unroll") for (int i = 0; i < 4; ++i)                          \
          GLDS16(bsp[i] + (kk), smem + (bufb) + 16384 + bflat[i] * 16); }

    STAGE(0, 0);

    #pragma unroll 1
    for (int t = 0; t < 16; ++t) {
        const int cur = (t & 1) * 32768;
        if (t < 15) {
            STAGE((t + 1) * 32, 32768 - cur);
            asm volatile("s_waitcnt vmcnt(8)" ::: "memory");   // stage t done
        } else {
            asm volatile("s_waitcnt vmcnt(0)" ::: "memory");
        }
        __builtin_amdgcn_s_barrier();        // all waves' stage t visible

        bf16x8 af[4], bfr[8];
        #pragma unroll
        for (int mf = 0; mf < 4; ++mf) {
            f32x4 lo = *(const f32x4*)(smem + cur + aoff[mf][0]);
            f32x4 hi = *(const f32x4*)(smem + cur + aoff[mf][1]);
            af[mf] = cvt8(lo, hi);
        }
        #pragma unroll
        for (int nf = 0; nf < 8; ++nf)
            bfr[nf] = *(const bf16x8*)(smem + cur + boff[nf]);
        #pragma unroll
        for (int mf = 0; mf < 4; ++mf)
            #pragma unroll
            for (int nf = 0; nf < 8; ++nf)
                acc[mf][nf] = __builtin_amdgcn_mfma_f32_16x16x32_bf16(
                    af[mf], bfr[nf], acc[mf][nf], 0, 0, 0);

        __builtin_amdgcn_s_barrier();        // buf may be overwritten next t
    }

    const int r4 = (lane >> 4) * 4;

    if (!FUSED) {
        #pragma unroll
        for (int mf = 0; mf < 4; ++mf)
            #pragma unroll
            for (int nf = 0; nf < 8; ++nf)
                #pragma unroll
                for (int j = 0; j < 4; ++j) {
                    int row = m0 + wr + mf * 16 + r4 + j;
                    int col = n0 + wc + nf * 16 + l15;
                    C[(size_t)row * DD + col] = f2b_hw(acc[mf][nf][j]);
                }
        return;
    }

    // ---- fused epilogue: P' = acc + bias -> Ps (bf16), gather Q[idx] ------
    const u16* qs = Qb + ((size_t)(m0 >> 11) << 20);   // batch * 2048 * 512

    float bi[8];
    #pragma unroll
    for (int nf = 0; nf < 8; ++nf)
        bi[nf] = bias[n0 + wc + nf * 16 + l15];

    u16* Ps = (u16*)smem;                    // [128][260] bf16, 66560 B
    #pragma unroll
    for (int mf = 0; mf < 4; ++mf)
        #pragma unroll
        for (int nf = 0; nf < 8; ++nf)
            #pragma unroll
            for (int j = 0; j < 4; ++j)
                Ps[(wr + mf * 16 + r4 + j) * 260 + wc + nf * 16 + l15] =
                    f2b_hw(acc[mf][nf][j] + bi[nf]);

    // depth-2 gather pipeline: two static register banks (rule #20)
    bf16x8 qA0[8], qA1[8];

#define QLOAD(BANK, k)                                                       \
    { const size_t rx = (size_t)iv[k].x * DD, ry = (size_t)iv[k].y * DD,     \
                   rz = (size_t)iv[k].z * DD, rw = (size_t)iv[k].w * DD;     \
      _Pragma("unroll") for (int cc = 0; cc < 2; ++cc) {                     \
          const int col = n0 + cc * 128 + l16 * 8;                           \
          BANK[cc*4+0] = *(const bf16x8*)(qs + rx + col);                    \
          BANK[cc*4+1] = *(const bf16x8*)(qs + ry + col);                    \
          BANK[cc*4+2] = *(const bf16x8*)(qs + rz + col);                    \
          BANK[cc*4+3] = *(const bf16x8*)(qs + rw + col);                    \
      } }

#define QCONSUME(BANK, k)                                                    \
    { f32x4 wv = *(const f32x4*)(wb + (size_t)(m0 + r0g + (k)) * 4);         \
      _Pragma("unroll") for (int cc = 0; cc < 2; ++cc) {                     \
          const int col = cc * 128 + l16 * 8;                                \
          bf16x8 p8 = *(const bf16x8*)(Ps + (r0g + (k)) * 260 + col);        \
          float o[8];                                                        \
          _Pragma("unroll") for (int j = 0; j < 8; ++j) {                    \
              float p = b2f((u16)p8[j]);                                     \
              float s;                                                       \
              s  = fmaxf(p + b2f((u16)BANK[cc*4+0][j]), 0.f) * wv[0];        \
              s += fmaxf(p + b2f((u16)BANK[cc*4+1][j]), 0.f) * wv[1];        \
              s += fmaxf(p + b2f((u16)BANK[cc*4+2][j]), 0.f) * wv[2];        \
              s += fmaxf(p + b2f((u16)BANK[cc*4+3][j]), 0.f) * wv[3];        \
              o[j] = s;                                                      \
          }                                                                  \
          float* op = out + (size_t)(m0 + r0g + (k)) * 1024 + 512 + n0 + col;\
          *(f32x4*)op       = (f32x4){o[0], o[1], o[2], o[3]};               \
          *(f32x4*)(op + 4) = (f32x4){o[4], o[5], o[6], o[7]};               \
      } }

    // issue first two gather batches before the barrier (in flight across it)
    QLOAD(qA0, 0);
    QLOAD(qA1, 1);
    __syncthreads();

    QCONSUME(qA0, 0); QLOAD(qA0, 2);
    QCONSUME(qA1, 1); QLOAD(qA1, 3);
    QCONSUME(qA0, 2); QLOAD(qA0, 4);
    QCONSUME(qA1, 3); QLOAD(qA1, 5);
    QCONSUME(qA0, 4); QLOAD(qA0, 6);
    QCONSUME(qA1, 5); QLOAD(qA1, 7);
    QCONSUME(qA0, 6);
    QCONSUME(qA1, 7);
}

extern "C" void kernel_launch(void* const* d_in, const int* in_sizes, int n_in,
                              void* d_out, int out_size, void* d_ws, size_t ws_size,
                              hipStream_t stream) {
    const float* fa   = (const float*)d_in[0];
    const float* fb   = (const float*)d_in[1];
    const float* W    = (const float*)d_in[2];
    const float* bias = (const float*)d_in[3];
    const int*   ca   = (const int*)d_in[4];
    const int*   cb   = (const int*)d_in[5];
    float* out = (float*)d_out;

    char* ws = (char*)d_ws;
    u16*   Qb   = (u16*)(ws);                       // 32 MB bf16 Q
    u16*   W2T  = (u16*)(ws + 33554432);            // 512 KB
    u16*   WdT  = (u16*)(ws + 34078720);            // 512 KB
    int*   idxb = (int*)(ws + 34603008);            // 512 KB
    float* wb   = (float*)(ws + 35127296);          // 512 KB

    topk_prep<<<320, 512, 0, stream>>>(ca, cb, idxb, wb, fa, out,
                                       W, W2T, WdT);

    dim3 gg(256, 2);
    gemm_kernel<false><<<gg, 256, 0, stream>>>(fb, WdT, Qb, nullptr, nullptr,
                                               nullptr, nullptr, nullptr);
    gemm_kernel<true><<<gg, 256, 0, stream>>>(fa, W2T, nullptr, idxb, wb,
                                              bias, Qb, out);
}

// Round 21
// 123.481 us; speedup vs baseline: 1.0508x; 1.0058x over previous
//
#include <hip/hip_runtime.h>
#include <hip/hip_bf16.h>
#include <cstdint>
#include <cstddef>

#define NA   2048
#define NB   2048
#define DD   512

typedef __attribute__((ext_vector_type(8))) short bf16x8;
typedef __attribute__((ext_vector_type(4))) float f32x4;
typedef unsigned short u16;
typedef unsigned int   u32;

__device__ __forceinline__ u16 f2b_hw(float f) {
    u32 w;
    asm("v_cvt_pk_bf16_f32 %0, %1, %2" : "=v"(w) : "v"(f), "v"(f));
    return (u16)w;
}
__device__ __forceinline__ float b2f(u16 h) {
    return __uint_as_float(((u32)h) << 16);
}
__device__ __forceinline__ u32 umin32(u32 a, u32 b) { return a < b ? a : b; }
__device__ __forceinline__ u32 umax32(u32 a, u32 b) { return a > b ? a : b; }
__device__ __forceinline__ u32 med3u(u32 a, u32 b, u32 c) {
    return umax32(umin32(a, b), umin32(umax32(a, b), c));   // -> v_med3_u32
}
__device__ __forceinline__ bf16x8 cvt8(f32x4 v0, f32x4 v1) {
    u32 w0, w1, w2, w3;
    asm("v_cvt_pk_bf16_f32 %0, %1, %2" : "=v"(w0) : "v"(v0[0]), "v"(v0[1]));
    asm("v_cvt_pk_bf16_f32 %0, %1, %2" : "=v"(w1) : "v"(v0[2]), "v"(v0[3]));
    asm("v_cvt_pk_bf16_f32 %0, %1, %2" : "=v"(w2) : "v"(v1[0]), "v"(v1[1]));
    asm("v_cvt_pk_bf16_f32 %0, %1, %2" : "=v"(w3) : "v"(v1[2]), "v"(v1[3]));
    union { u32 u[4]; bf16x8 v; } cv;
    cv.u[0] = w0; cv.u[1] = w1; cv.u[2] = w2; cv.u[3] = w3;
    return cv.v;
}

#define GLDS16(gsrc, ldst)                                                  \
    __builtin_amdgcn_global_load_lds(                                       \
        (const __attribute__((address_space(1))) void*)(gsrc),              \
        (__attribute__((address_space(3))) void*)(ldst), 16, 0, 0)

// ---------------------------------------------------------------------------
// Fused topk + copy + prep_w. 1D grid of 320 blocks x 512 threads (as R20).
// ---------------------------------------------------------------------------
__global__ __launch_bounds__(512) void topk_prep(
    const int* __restrict__ ca, const int* __restrict__ cb,
    int* __restrict__ idx_out, float* __restrict__ w_out,
    const float* __restrict__ fa, float* __restrict__ out,
    const float* __restrict__ W, u16* __restrict__ W2T,
    u16* __restrict__ WdT) {

    __shared__ __align__(16) char smem[33280];
    const int bid = blockIdx.x;
    const int tid = threadIdx.x;

    if (bid >= 256) {
        float (*s2)[65] = (float(*)[65])smem;
        float (*sd)[65] = (float(*)[65])(smem + 16640);
        const int pid = bid - 256;
        const int kb = (pid >> 3) * 64, nb = (pid & 7) * 64;
        const int c = tid & 63, r0 = tid >> 6;
        #pragma unroll
        for (int p = 0; p < 8; ++p) {
            int r = p * 8 + r0;
            float w1 = W[(size_t)(kb + r) * DD + nb + c];
            float w2 = W[(size_t)(512 + kb + r) * DD + nb + c];
            s2[r][c] = w2;
            sd[r][c] = w1 - w2;
        }
        __syncthreads();
        #pragma unroll
        for (int p = 0; p < 8; ++p) {
            int n = p * 8 + r0;
            W2T[(size_t)(nb + n) * DD + kb + c] = f2b_hw(s2[c][n]);
            WdT[(size_t)(nb + n) * DD + kb + c] = f2b_hw(sd[c][n]);
        }
        return;
    }

    u32* pcb  = (u32*)smem;
    u32* part = (u32*)(smem + 8192);
    const int b  = bid >> 4;
    const int i0 = (bid & 15) << 7;
    for (int p = tid; p < NB; p += 512) {
        const int* c = cb + ((size_t)b * NB + p) * 3;
        pcb[p] = (u32)c[0] | ((u32)c[1] << 8) | ((u32)c[2] << 16);
    }
    __syncthreads();

    int q = tid & 127, g = tid >> 7;
    int i = i0 + q;
    const int* ac = ca + ((size_t)b * NA + i) * 3;
    int ax = ac[0], ay = ac[1], az = ac[2];

    const float* src = fa + (size_t)bid * 128 * DD;
    float*       dst = out + (size_t)bid * 128 * 1024;

    u32 k0 = ~0u, k1 = ~0u, k2 = ~0u, k3 = ~0u;
    int j0 = g * 512;

    #pragma unroll 1
    for (int c = 0; c < 4; ++c) {
        f32x4 tr[8];
        #pragma unroll
        for (int k = 0; k < 8; ++k) {
            int f = c * 4096 + k * 512 + tid;
            tr[k] = *(const f32x4*)(src + (size_t)(f >> 7) * DD + (f & 127) * 4);
        }
        int jbase = j0 + c * 128;
        #pragma unroll 8
        for (int jj = 0; jj < 128; ++jj) {
            int j = jbase + jj;
            u32 p = pcb[j];
            int dx = ax - (int)(p & 255u);
            int dy = ay - (int)((p >> 8) & 255u);
            int dz = az - (int)(p >> 16);
            u32 s = (u32)(__mul24(dx, dx) + __mul24(dy, dy) + __mul24(dz, dz));
            u32 key = (s << 11) | (u32)j;
            u32 nk0 = umin32(k0, key);
            u32 nk1 = med3u(key, k0, k1);
            u32 nk2 = med3u(key, k1, k2);
            u32 nk3 = med3u(key, k2, k3);
            k0 = nk0; k1 = nk1; k2 = nk2; k3 = nk3;
        }
        #pragma unroll
        for (int k = 0; k < 8; ++k) {
            int f = c * 4096 + k * 512 + tid;
            *(f32x4*)(dst + (size_t)(f >> 7) * 1024 + (f & 127) * 4) = tr[k];
        }
    }

    if (g) {
        u32* pp = &part[((g - 1) * 128 + q) * 4];
        pp[0] = k0; pp[1] = k1; pp[2] = k2; pp[3] = k3;
    }
    __syncthreads();
    if (g == 0) {
        #pragma unroll
        for (int L = 0; L < 3; ++L) {
            const u32* pp = &part[(L * 128 + q) * 4];
            #pragma unroll
            for (int t = 0; t < 4; ++t) {
                u32 key = pp[t];
                u32 nk0 = umin32(k0, key);
                u32 nk1 = med3u(key, k0, k1);
                u32 nk2 = med3u(key, k1, k2);
                u32 nk3 = med3u(key, k2, k3);
                k0 = nk0; k1 = nk1; k2 = nk2; k3 = nk3;
            }
        }
        size_t o = ((size_t)b * NA + i) * 4;
        u32 ks[4] = {k0, k1, k2, k3};
        #pragma unroll
        for (int t = 0; t < 4; ++t) {
            idx_out[o + t] = (int)(ks[t] & 2047u);
            float d = sqrtf((float)(ks[t] >> 11)) * (1.0f / 128.0f);
            w_out[o + t] = 0.5f - fminf(d, 0.5f);
        }
    }
}

// ---------------------------------------------------------------------------
// C = A(f32) @ BT^T(bf16). BM=64, BN=256, BK=32, 4 waves (32m x 128n each).
// 24KB/buffer x2 = 48KB LDS -> 3 blocks/CU: staggered retirement overlaps
// one block's gather tail with another's K-loop (vs lockstep at 2/CU).
// A staged f32 via GLDS16 (src XOR-swizzled), cvt_pk->bf16 at fragment read.
// Counted vmcnt(6). FUSED: bias+relu+Q[idx]-gather tail, depth-2 banks.
// ---------------------------------------------------------------------------
template<bool FUSED>
__global__ __launch_bounds__(256, 1) void gemm_kernel(
    const float* __restrict__ A, const u16* __restrict__ BT,
    u16* __restrict__ C, const int* __restrict__ idxb,
    const float* __restrict__ wb, const float* __restrict__ bias,
    const u16* __restrict__ Qb, float* __restrict__ out) {

    __shared__ __align__(16) char smem[49152];   // 2 x (8KB A + 16KB B)

    const int tid  = threadIdx.x;
    const int lane = tid & 63;
    const int wave = tid >> 6;
    const int mb   = blockIdx.x;                 // 0..511 (64-row tiles)
    const int m0   = FUSED ? ((((mb & 7) << 6) | (mb >> 3)) << 6) : (mb << 6);
    const int n0   = blockIdx.y << 8;
    const int l15  = lane & 15;
    const int fq   = lane >> 4;                  // 0..3
    const int wr   = (wave >> 1) << 5;           // 0 / 32
    const int wc   = (wave & 1) << 7;            // 0 / 128

    // ---- staging descriptors: LDS dest linear, SOURCE pre-swizzled --------
    int aflat[2]; const float* asp[2];
    #pragma unroll
    for (int i = 0; i < 2; ++i) {
        int flat = i * 256 + tid;                // A: 64 rows x 8 f32 16B-quads
        int row = flat >> 3, pq = flat & 7;
        aflat[i] = flat;
        asp[i] = A + (size_t)(m0 + row) * DD + ((pq ^ (row & 7)) << 2);
    }
    int bflat[4]; const u16* bsp[4];
    #pragma unroll
    for (int i = 0; i < 4; ++i) {
        int flat = i * 256 + tid;                // B: 256 rows x 4 bf16 quads
        int row = flat >> 2, pq = flat & 3;
        bflat[i] = flat;
        bsp[i] = BT + (size_t)(n0 + row) * DD + ((pq ^ ((row >> 1) & 3)) << 3);
    }

    // ---- fragment LDS byte offsets (same involution on read) --------------
    int aoff[2][2], boff[8];
    #pragma unroll
    for (int mf = 0; mf < 2; ++mf) {
        int R = wr + mf * 16 + l15;              // 0..63
        aoff[mf][0] = R * 128 + (((2 * fq) ^ (R & 7)) << 4);
        aoff[mf][1] = R * 128 + (((2 * fq + 1) ^ (R & 7)) << 4);
    }
    #pragma unroll
    for (int nf = 0; nf < 8; ++nf) {
        int R = wc + nf * 16 + l15;              // 0..255
        boff[nf] = 8192 + R * 64 + ((fq ^ ((R >> 1) & 3)) << 4);
    }

    // FUSED: hoist idx loads (ready at block start; frees tail latency)
    const int g16 = tid >> 4, l16 = tid & 15;
    const int r0g = g16 * 4;                     // 16 groups x 4 rows = 64
    int4 iv[4];
    if (FUSED) {
        #pragma unroll
        for (int k = 0; k < 4; ++k)
            iv[k] = *(const int4*)(idxb + (size_t)(m0 + r0g + k) * 4);
    }

    f32x4 acc[2][8];
    #pragma unroll
    for (int mf = 0; mf < 2; ++mf)
        #pragma unroll
        for (int nf = 0; nf < 8; ++nf)
            acc[mf][nf] = (f32x4){0.f, 0.f, 0.f, 0.f};

#define STAGE(kk, bufb)                                                      \
    { _Pragma("unroll") for (int i = 0; i < 2; ++i)                          \
          GLDS16(asp[i] + (kk), smem + (bufb) + aflat[i] * 16);              \
      _Pragma("unroll") for (int i = 0; i < 4; ++i)                          \
          GLDS16(bsp[i] + (kk), smem + (bufb) + 8192 + bflat[i] * 16); }

    STAGE(0, 0);

    #pragma unroll 1
    for (int t = 0; t < 16; ++t) {
        const int cur = (t & 1) * 24576;
        if (t < 15) {
            STAGE((t + 1) * 32, 24576 - cur);
            asm volatile("s_waitcnt vmcnt(6)" ::: "memory");   // stage t done
        } else {
            asm volatile("s_waitcnt vmcnt(0)" ::: "memory");
        }
        __builtin_amdgcn_s_barrier();        // all waves' stage t visible

        bf16x8 af[2], bfr[8];
        #pragma unroll
        for (int mf = 0; mf < 2; ++mf) {
            f32x4 lo = *(const f32x4*)(smem + cur + aoff[mf][0]);
            f32x4 hi = *(const f32x4*)(smem + cur + aoff[mf][1]);
            af[mf] = cvt8(lo, hi);
        }
        #pragma unroll
        for (int nf = 0; nf < 8; ++nf)
            bfr[nf] = *(const bf16x8*)(smem + cur + boff[nf]);
        #pragma unroll
        for (int mf = 0; mf < 2; ++mf)
            #pragma unroll
            for (int nf = 0; nf < 8; ++nf)
                acc[mf][nf] = __builtin_amdgcn_mfma_f32_16x16x32_bf16(
                    af[mf], bfr[nf], acc[mf][nf], 0, 0, 0);

        __builtin_amdgcn_s_barrier();        // buf may be overwritten next t
    }

    const int r4 = (lane >> 4) * 4;

    if (!FUSED) {
        #pragma unroll
        for (int mf = 0; mf < 2; ++mf)
            #pragma unroll
            for (int nf = 0; nf < 8; ++nf)
                #pragma unroll
                for (int j = 0; j < 4; ++j) {
                    int row = m0 + wr + mf * 16 + r4 + j;
                    int col = n0 + wc + nf * 16 + l15;
                    C[(size_t)row * DD + col] = f2b_hw(acc[mf][nf][j]);
                }
        return;
    }

    // ---- fused epilogue: P' = acc + bias -> Ps (bf16), gather Q[idx] ------
    const u16* qs = Qb + ((size_t)(m0 >> 11) << 20);   // batch * 2048 * 512

    float bi[8];
    #pragma unroll
    for (int nf = 0; nf < 8; ++nf)
        bi[nf] = bias[n0 + wc + nf * 16 + l15];

    u16* Ps = (u16*)smem;                    // [64][260] bf16, 33280 B
    #pragma unroll
    for (int mf = 0; mf < 2; ++mf)
        #pragma unroll
        for (int nf = 0; nf < 8; ++nf)
            #pragma unroll
            for (int j = 0; j < 4; ++j)
                Ps[(wr + mf * 16 + r4 + j) * 260 + wc + nf * 16 + l15] =
                    f2b_hw(acc[mf][nf][j] + bi[nf]);

    // depth-2 gather pipeline: two static register banks (rule #20)
    bf16x8 qA0[8], qA1[8];

#define QLOAD(BANK, k)                                                       \
    { const size_t rx = (size_t)iv[k].x * DD, ry = (size_t)iv[k].y * DD,     \
                   rz = (size_t)iv[k].z * DD, rw = (size_t)iv[k].w * DD;     \
      _Pragma("unroll") for (int cc = 0; cc < 2; ++cc) {                     \
          const int col = n0 + cc * 128 + l16 * 8;                           \
          BANK[cc*4+0] = *(const bf16x8*)(qs + rx + col);                    \
          BANK[cc*4+1] = *(const bf16x8*)(qs + ry + col);                    \
          BANK[cc*4+2] = *(const bf16x8*)(qs + rz + col);                    \
          BANK[cc*4+3] = *(const bf16x8*)(qs + rw + col);                    \
      } }

#define QCONSUME(BANK, k)                                                    \
    { f32x4 wv = *(const f32x4*)(wb + (size_t)(m0 + r0g + (k)) * 4);         \
      _Pragma("unroll") for (int cc = 0; cc < 2; ++cc) {                     \
          const int col = cc * 128 + l16 * 8;                                \
          bf16x8 p8 = *(const bf16x8*)(Ps + (r0g + (k)) * 260 + col);        \
          float o[8];                                                        \
          _Pragma("unroll") for (int j = 0; j < 8; ++j) {                    \
              float p = b2f((u16)p8[j]);                                     \
              float s;                                                       \
              s  = fmaxf(p + b2f((u16)BANK[cc*4+0][j]), 0.f) * wv[0];        \
              s += fmaxf(p + b2f((u16)BANK[cc*4+1][j]), 0.f) * wv[1];        \
              s += fmaxf(p + b2f((u16)BANK[cc*4+2][j]), 0.f) * wv[2];        \
              s += fmaxf(p + b2f((u16)BANK[cc*4+3][j]), 0.f) * wv[3];        \
              o[j] = s;                                                      \
          }                                                                  \
          float* op = out + (size_t)(m0 + r0g + (k)) * 1024 + 512 + n0 + col;\
          *(f32x4*)op       = (f32x4){o[0], o[1], o[2], o[3]};               \
          *(f32x4*)(op + 4) = (f32x4){o[4], o[5], o[6], o[7]};               \
      } }

    // issue first two gather batches before the barrier (in flight across it)
    QLOAD(qA0, 0);
    QLOAD(qA1, 1);
    __syncthreads();

    QCONSUME(qA0, 0); QLOAD(qA0, 2);
    QCONSUME(qA1, 1); QLOAD(qA1, 3);
    QCONSUME(qA0, 2);
    QCONSUME(qA1, 3);
}

extern "C" void kernel_launch(void* const* d_in, const int* in_sizes, int n_in,
                              void* d_out, int out_size, void* d_ws, size_t ws_size,
                              hipStream_t stream) {
    const float* fa   = (const float*)d_in[0];
    const float* fb   = (const float*)d_in[1];
    const float* W    = (const float*)d_in[2];
    const float* bias = (const float*)d_in[3];
    const int*   ca   = (const int*)d_in[4];
    const int*   cb   = (const int*)d_in[5];
    float* out = (float*)d_out;

    char* ws = (char*)d_ws;
    u16*   Qb   = (u16*)(ws);                       // 32 MB bf16 Q
    u16*   W2T  = (u16*)(ws + 33554432);            // 512 KB
    u16*   WdT  = (u16*)(ws + 34078720);            // 512 KB
    int*   idxb = (int*)(ws + 34603008);            // 512 KB
    float* wb   = (float*)(ws + 35127296);          // 512 KB

    topk_prep<<<320, 512, 0, stream>>>(ca, cb, idxb, wb, fa, out,
                                       W, W2T, WdT);

    dim3 gg(512, 2);
    gemm_kernel<false><<<gg, 256, 0, stream>>>(fb, WdT, Qb, nullptr, nullptr,
                                               nullptr, nullptr, nullptr);
    gemm_kernel<true><<<gg, 256, 0, stream>>>(fa, W2T, nullptr, idxb, wb,
                                              bias, Qb, out);
}

// Round 22
// 123.243 us; speedup vs baseline: 1.0528x; 1.0019x over previous
//
#include <hip/hip_runtime.h>
#include <hip/hip_bf16.h>
#include <cstdint>
#include <cstddef>

#define NA   2048
#define NB   2048
#define DD   512

typedef __attribute__((ext_vector_type(8))) short bf16x8;
typedef __attribute__((ext_vector_type(4))) float f32x4;
typedef unsigned short u16;
typedef unsigned int   u32;

__device__ __forceinline__ u16 f2b_hw(float f) {
    u32 w;
    asm("v_cvt_pk_bf16_f32 %0, %1, %2" : "=v"(w) : "v"(f), "v"(f));
    return (u16)w;
}
__device__ __forceinline__ float b2f(u16 h) {
    return __uint_as_float(((u32)h) << 16);
}
__device__ __forceinline__ u32 umin32(u32 a, u32 b) { return a < b ? a : b; }
__device__ __forceinline__ u32 umax32(u32 a, u32 b) { return a > b ? a : b; }
__device__ __forceinline__ u32 med3u(u32 a, u32 b, u32 c) {
    return umax32(umin32(a, b), umin32(umax32(a, b), c));   // -> v_med3_u32
}
__device__ __forceinline__ bf16x8 cvt8(f32x4 v0, f32x4 v1) {
    u32 w0, w1, w2, w3;
    asm("v_cvt_pk_bf16_f32 %0, %1, %2" : "=v"(w0) : "v"(v0[0]), "v"(v0[1]));
    asm("v_cvt_pk_bf16_f32 %0, %1, %2" : "=v"(w1) : "v"(v0[2]), "v"(v0[3]));
    asm("v_cvt_pk_bf16_f32 %0, %1, %2" : "=v"(w2) : "v"(v1[0]), "v"(v1[1]));
    asm("v_cvt_pk_bf16_f32 %0, %1, %2" : "=v"(w3) : "v"(v1[2]), "v"(v1[3]));
    union { u32 u[4]; bf16x8 v; } cv;
    cv.u[0] = w0; cv.u[1] = w1; cv.u[2] = w2; cv.u[3] = w3;
    return cv.v;
}

#define GLDS16(gsrc, ldst)                                                  \
    __builtin_amdgcn_global_load_lds(                                       \
        (const __attribute__((address_space(1))) void*)(gsrc),              \
        (__attribute__((address_space(3))) void*)(ldst), 16, 0, 0)

// ---------------------------------------------------------------------------
// Fused topk + copy + prep_w. 1D grid of 320 blocks x 512 threads (as R21).
// ---------------------------------------------------------------------------
__global__ __launch_bounds__(512) void topk_prep(
    const int* __restrict__ ca, const int* __restrict__ cb,
    int* __restrict__ idx_out, float* __restrict__ w_out,
    const float* __restrict__ fa, float* __restrict__ out,
    const float* __restrict__ W, u16* __restrict__ W2T,
    u16* __restrict__ WdT) {

    __shared__ __align__(16) char smem[33280];
    const int bid = blockIdx.x;
    const int tid = threadIdx.x;

    if (bid >= 256) {
        float (*s2)[65] = (float(*)[65])smem;
        float (*sd)[65] = (float(*)[65])(smem + 16640);
        const int pid = bid - 256;
        const int kb = (pid >> 3) * 64, nb = (pid & 7) * 64;
        const int c = tid & 63, r0 = tid >> 6;
        #pragma unroll
        for (int p = 0; p < 8; ++p) {
            int r = p * 8 + r0;
            float w1 = W[(size_t)(kb + r) * DD + nb + c];
            float w2 = W[(size_t)(512 + kb + r) * DD + nb + c];
            s2[r][c] = w2;
            sd[r][c] = w1 - w2;
        }
        __syncthreads();
        #pragma unroll
        for (int p = 0; p < 8; ++p) {
            int n = p * 8 + r0;
            W2T[(size_t)(nb + n) * DD + kb + c] = f2b_hw(s2[c][n]);
            WdT[(size_t)(nb + n) * DD + kb + c] = f2b_hw(sd[c][n]);
        }
        return;
    }

    u32* pcb  = (u32*)smem;
    u32* part = (u32*)(smem + 8192);
    const int b  = bid >> 4;
    const int i0 = (bid & 15) << 7;
    for (int p = tid; p < NB; p += 512) {
        const int* c = cb + ((size_t)b * NB + p) * 3;
        pcb[p] = (u32)c[0] | ((u32)c[1] << 8) | ((u32)c[2] << 16);
    }
    __syncthreads();

    int q = tid & 127, g = tid >> 7;
    int i = i0 + q;
    const int* ac = ca + ((size_t)b * NA + i) * 3;
    int ax = ac[0], ay = ac[1], az = ac[2];

    const float* src = fa + (size_t)bid * 128 * DD;
    float*       dst = out + (size_t)bid * 128 * 1024;

    u32 k0 = ~0u, k1 = ~0u, k2 = ~0u, k3 = ~0u;
    int j0 = g * 512;

    #pragma unroll 1
    for (int c = 0; c < 4; ++c) {
        f32x4 tr[8];
        #pragma unroll
        for (int k = 0; k < 8; ++k) {
            int f = c * 4096 + k * 512 + tid;
            tr[k] = *(const f32x4*)(src + (size_t)(f >> 7) * DD + (f & 127) * 4);
        }
        int jbase = j0 + c * 128;
        #pragma unroll 8
        for (int jj = 0; jj < 128; ++jj) {
            int j = jbase + jj;
            u32 p = pcb[j];
            int dx = ax - (int)(p & 255u);
            int dy = ay - (int)((p >> 8) & 255u);
            int dz = az - (int)(p >> 16);
            u32 s = (u32)(__mul24(dx, dx) + __mul24(dy, dy) + __mul24(dz, dz));
            u32 key = (s << 11) | (u32)j;
            u32 nk0 = umin32(k0, key);
            u32 nk1 = med3u(key, k0, k1);
            u32 nk2 = med3u(key, k1, k2);
            u32 nk3 = med3u(key, k2, k3);
            k0 = nk0; k1 = nk1; k2 = nk2; k3 = nk3;
        }
        #pragma unroll
        for (int k = 0; k < 8; ++k) {
            int f = c * 4096 + k * 512 + tid;
            *(f32x4*)(dst + (size_t)(f >> 7) * 1024 + (f & 127) * 4) = tr[k];
        }
    }

    if (g) {
        u32* pp = &part[((g - 1) * 128 + q) * 4];
        pp[0] = k0; pp[1] = k1; pp[2] = k2; pp[3] = k3;
    }
    __syncthreads();
    if (g == 0) {
        #pragma unroll
        for (int L = 0; L < 3; ++L) {
            const u32* pp = &part[(L * 128 + q) * 4];
            #pragma unroll
            for (int t = 0; t < 4; ++t) {
                u32 key = pp[t];
                u32 nk0 = umin32(k0, key);
                u32 nk1 = med3u(key, k0, k1);
                u32 nk2 = med3u(key, k1, k2);
                u32 nk3 = med3u(key, k2, k3);
                k0 = nk0; k1 = nk1; k2 = nk2; k3 = nk3;
            }
        }
        size_t o = ((size_t)b * NA + i) * 4;
        u32 ks[4] = {k0, k1, k2, k3};
        #pragma unroll
        for (int t = 0; t < 4; ++t) {
            idx_out[o + t] = (int)(ks[t] & 2047u);
            float d = sqrtf((float)(ks[t] >> 11)) * (1.0f / 128.0f);
            w_out[o + t] = 0.5f - fminf(d, 0.5f);
        }
    }
}

// ---------------------------------------------------------------------------
// C = A(f32) @ BT^T(bf16). BM=64, BN=256, BK=32, 4 waves (32m x 128n each).
// 24KB/buffer x2 = 48KB LDS -> 3 blocks/CU. A staged f32 via GLDS16 (src
// XOR-swizzled), cvt_pk->bf16 at fragment read. Counted vmcnt(6).
// FUSED tail: QLOAD(0,1) issued BEFORE the Ps write (gathers depend only on
// iv/Qb, so the Ps-write span + barrier covers their latency), then
// bias+relu gather with depth-2 banks.
// ---------------------------------------------------------------------------
template<bool FUSED>
__global__ __launch_bounds__(256, 1) void gemm_kernel(
    const float* __restrict__ A, const u16* __restrict__ BT,
    u16* __restrict__ C, const int* __restrict__ idxb,
    const float* __restrict__ wb, const float* __restrict__ bias,
    const u16* __restrict__ Qb, float* __restrict__ out) {

    __shared__ __align__(16) char smem[49152];   // 2 x (8KB A + 16KB B)

    const int tid  = threadIdx.x;
    const int lane = tid & 63;
    const int wave = tid >> 6;
    const int mb   = blockIdx.x;                 // 0..511 (64-row tiles)
    const int m0   = FUSED ? ((((mb & 7) << 6) | (mb >> 3)) << 6) : (mb << 6);
    const int n0   = blockIdx.y << 8;
    const int l15  = lane & 15;
    const int fq   = lane >> 4;                  // 0..3
    const int wr   = (wave >> 1) << 5;           // 0 / 32
    const int wc   = (wave & 1) << 7;            // 0 / 128

    // ---- staging descriptors: LDS dest linear, SOURCE pre-swizzled --------
    int aflat[2]; const float* asp[2];
    #pragma unroll
    for (int i = 0; i < 2; ++i) {
        int flat = i * 256 + tid;                // A: 64 rows x 8 f32 16B-quads
        int row = flat >> 3, pq = flat & 7;
        aflat[i] = flat;
        asp[i] = A + (size_t)(m0 + row) * DD + ((pq ^ (row & 7)) << 2);
    }
    int bflat[4]; const u16* bsp[4];
    #pragma unroll
    for (int i = 0; i < 4; ++i) {
        int flat = i * 256 + tid;                // B: 256 rows x 4 bf16 quads
        int row = flat >> 2, pq = flat & 3;
        bflat[i] = flat;
        bsp[i] = BT + (size_t)(n0 + row) * DD + ((pq ^ ((row >> 1) & 3)) << 3);
    }

    // ---- fragment LDS byte offsets (same involution on read) --------------
    int aoff[2][2], boff[8];
    #pragma unroll
    for (int mf = 0; mf < 2; ++mf) {
        int R = wr + mf * 16 + l15;              // 0..63
        aoff[mf][0] = R * 128 + (((2 * fq) ^ (R & 7)) << 4);
        aoff[mf][1] = R * 128 + (((2 * fq + 1) ^ (R & 7)) << 4);
    }
    #pragma unroll
    for (int nf = 0; nf < 8; ++nf) {
        int R = wc + nf * 16 + l15;              // 0..255
        boff[nf] = 8192 + R * 64 + ((fq ^ ((R >> 1) & 3)) << 4);
    }

    // FUSED: hoist idx loads (ready at block start; frees tail latency)
    const int g16 = tid >> 4, l16 = tid & 15;
    const int r0g = g16 * 4;                     // 16 groups x 4 rows = 64
    int4 iv[4];
    if (FUSED) {
        #pragma unroll
        for (int k = 0; k < 4; ++k)
            iv[k] = *(const int4*)(idxb + (size_t)(m0 + r0g + k) * 4);
    }

    f32x4 acc[2][8];
    #pragma unroll
    for (int mf = 0; mf < 2; ++mf)
        #pragma unroll
        for (int nf = 0; nf < 8; ++nf)
            acc[mf][nf] = (f32x4){0.f, 0.f, 0.f, 0.f};

#define STAGE(kk, bufb)                                                      \
    { _Pragma("unroll") for (int i = 0; i < 2; ++i)                          \
          GLDS16(asp[i] + (kk), smem + (bufb) + aflat[i] * 16);              \
      _Pragma("unroll") for (int i = 0; i < 4; ++i)                          \
          GLDS16(bsp[i] + (kk), smem + (bufb) + 8192 + bflat[i] * 16); }

    STAGE(0, 0);

    #pragma unroll 1
    for (int t = 0; t < 16; ++t) {
        const int cur = (t & 1) * 24576;
        if (t < 15) {
            STAGE((t + 1) * 32, 24576 - cur);
            asm volatile("s_waitcnt vmcnt(6)" ::: "memory");   // stage t done
        } else {
            asm volatile("s_waitcnt vmcnt(0)" ::: "memory");
        }
        __builtin_amdgcn_s_barrier();        // all waves' stage t visible

        bf16x8 af[2], bfr[8];
        #pragma unroll
        for (int mf = 0; mf < 2; ++mf) {
            f32x4 lo = *(const f32x4*)(smem + cur + aoff[mf][0]);
            f32x4 hi = *(const f32x4*)(smem + cur + aoff[mf][1]);
            af[mf] = cvt8(lo, hi);
        }
        #pragma unroll
        for (int nf = 0; nf < 8; ++nf)
            bfr[nf] = *(const bf16x8*)(smem + cur + boff[nf]);
        #pragma unroll
        for (int mf = 0; mf < 2; ++mf)
            #pragma unroll
            for (int nf = 0; nf < 8; ++nf)
                acc[mf][nf] = __builtin_amdgcn_mfma_f32_16x16x32_bf16(
                    af[mf], bfr[nf], acc[mf][nf], 0, 0, 0);

        __builtin_amdgcn_s_barrier();        // buf may be overwritten next t
    }

    const int r4 = (lane >> 4) * 4;

    if (!FUSED) {
        #pragma unroll
        for (int mf = 0; mf < 2; ++mf)
            #pragma unroll
            for (int nf = 0; nf < 8; ++nf)
                #pragma unroll
                for (int j = 0; j < 4; ++j) {
                    int row = m0 + wr + mf * 16 + r4 + j;
                    int col = n0 + wc + nf * 16 + l15;
                    C[(size_t)row * DD + col] = f2b_hw(acc[mf][nf][j]);
                }
        return;
    }

    // ---- fused epilogue --------------------------------------------------
    const u16* qs = Qb + ((size_t)(m0 >> 11) << 20);   // batch * 2048 * 512

    // depth-2 gather pipeline: two static register banks (rule #20)
    bf16x8 qA0[8], qA1[8];

#define QLOAD(BANK, k)                                                       \
    { const size_t rx = (size_t)iv[k].x * DD, ry = (size_t)iv[k].y * DD,     \
                   rz = (size_t)iv[k].z * DD, rw = (size_t)iv[k].w * DD;     \
      _Pragma("unroll") for (int cc = 0; cc < 2; ++cc) {                     \
          const int col = n0 + cc * 128 + l16 * 8;                           \
          BANK[cc*4+0] = *(const bf16x8*)(qs + rx + col);                    \
          BANK[cc*4+1] = *(const bf16x8*)(qs + ry + col);                    \
          BANK[cc*4+2] = *(const bf16x8*)(qs + rz + col);                    \
          BANK[cc*4+3] = *(const bf16x8*)(qs + rw + col);                    \
      } }

    // issue the first two gather batches BEFORE the Ps write: they depend
    // only on iv/Qb, so the Ps-write span + barrier covers their latency.
    QLOAD(qA0, 0);
    QLOAD(qA1, 1);

    float bi[8];
    #pragma unroll
    for (int nf = 0; nf < 8; ++nf)
        bi[nf] = bias[n0 + wc + nf * 16 + l15];

    u16* Ps = (u16*)smem;                    // [64][260] bf16, 33280 B
    #pragma unroll
    for (int mf = 0; mf < 2; ++mf)
        #pragma unroll
        for (int nf = 0; nf < 8; ++nf)
            #pragma unroll
            for (int j = 0; j < 4; ++j)
                Ps[(wr + mf * 16 + r4 + j) * 260 + wc + nf * 16 + l15] =
                    f2b_hw(acc[mf][nf][j] + bi[nf]);
    __syncthreads();

#define QCONSUME(BANK, k)                                                    \
    { f32x4 wv = *(const f32x4*)(wb + (size_t)(m0 + r0g + (k)) * 4);         \
      _Pragma("unroll") for (int cc = 0; cc < 2; ++cc) {                     \
          const int col = cc * 128 + l16 * 8;                                \
          bf16x8 p8 = *(const bf16x8*)(Ps + (r0g + (k)) * 260 + col);        \
          float o[8];                                                        \
          _Pragma("unroll") for (int j = 0; j < 8; ++j) {                    \
              float p = b2f((u16)p8[j]);                                     \
              float s;                                                       \
              s  = fmaxf(p + b2f((u16)BANK[cc*4+0][j]), 0.f) * wv[0];        \
              s += fmaxf(p + b2f((u16)BANK[cc*4+1][j]), 0.f) * wv[1];        \
              s += fmaxf(p + b2f((u16)BANK[cc*4+2][j]), 0.f) * wv[2];        \
              s += fmaxf(p + b2f((u16)BANK[cc*4+3][j]), 0.f) * wv[3];        \
              o[j] = s;                                                      \
          }                                                                  \
          float* op = out + (size_t)(m0 + r0g + (k)) * 1024 + 512 + n0 + col;\
          *(f32x4*)op       = (f32x4){o[0], o[1], o[2], o[3]};               \
          *(f32x4*)(op + 4) = (f32x4){o[4], o[5], o[6], o[7]};               \
      } }

    QCONSUME(qA0, 0); QLOAD(qA0, 2);
    QCONSUME(qA1, 1); QLOAD(qA1, 3);
    QCONSUME(qA0, 2);
    QCONSUME(qA1, 3);
}

extern "C" void kernel_launch(void* const* d_in, const int* in_sizes, int n_in,
                              void* d_out, int out_size, void* d_ws, size_t ws_size,
                              hipStream_t stream) {
    const float* fa   = (const float*)d_in[0];
    const float* fb   = (const float*)d_in[1];
    const float* W    = (const float*)d_in[2];
    const float* bias = (const float*)d_in[3];
    const int*   ca   = (const int*)d_in[4];
    const int*   cb   = (const int*)d_in[5];
    float* out = (float*)d_out;

    char* ws = (char*)d_ws;
    u16*   Qb   = (u16*)(ws);                       // 32 MB bf16 Q
    u16*   W2T  = (u16*)(ws + 33554432);            // 512 KB
    u16*   WdT  = (u16*)(ws + 34078720);            // 512 KB
    int*   idxb = (int*)(ws + 34603008);            // 512 KB
    float* wb   = (float*)(ws + 35127296);          // 512 KB

    topk_prep<<<320, 512, 0, stream>>>(ca, cb, idxb, wb, fa, out,
                                       W, W2T, WdT);

    dim3 gg(512, 2);
    gemm_kernel<false><<<gg, 256, 0, stream>>>(fb, WdT, Qb, nullptr, nullptr,
                                               nullptr, nullptr, nullptr);
    gemm_kernel<true><<<gg, 256, 0, stream>>>(fa, W2T, nullptr, idxb, wb,
                                              bias, Qb, out);
}